// Round 3
// baseline (4523.368 us; speedup 1.0000x reference)
//
#include <hip/hip_runtime.h>

using bf16x8 = __attribute__((ext_vector_type(8))) short;
using f32x4  = __attribute__((ext_vector_type(4))) float;

#if defined(__has_builtin)
#  if __has_builtin(__builtin_amdgcn_fdot2_f32_bf16)
#    define HAS_BF16_DOT 1
#  endif
#endif
#ifndef HAS_BF16_DOT
#  define HAS_BF16_DOT 0
#endif

#if HAS_BF16_DOT
typedef __bf16 bf16x2v __attribute__((ext_vector_type(2)));
#endif

__device__ inline float bf2f(unsigned short h){
  union { unsigned int u; float f; } v; v.u = ((unsigned int)h) << 16; return v.f;
}
__device__ inline unsigned short f2b(float x){
  union { float f; unsigned int u; } v; v.f = x;
  unsigned int r = (v.u + 0x7FFFu + ((v.u >> 16) & 1u)) >> 16;
  return (unsigned short)r;
}
__device__ inline unsigned int pack2(float a, float b){
  return (unsigned int)f2b(a) | ((unsigned int)f2b(b) << 16);
}
__device__ inline float bflo(unsigned int u){
  union { unsigned int u; float f; } v; v.u = u << 16; return v.f;
}
__device__ inline float bfhi(unsigned int u){
  union { unsigned int u; float f; } v; v.u = u & 0xffff0000u; return v.f;
}
// packed bf16 pair dot: acc += w.lo*x.lo + w.hi*x.hi
__device__ inline float dot2p(unsigned int w, unsigned int x, float acc){
#if HAS_BF16_DOT
  return __builtin_amdgcn_fdot2_f32_bf16(
      __builtin_bit_cast(bf16x2v, w), __builtin_bit_cast(bf16x2v, x), acc, false);
#else
  return fmaf(bfhi(w), bfhi(x), fmaf(bflo(w), bflo(x), acc));
#endif
}
__device__ inline float tanh_fast(float x){
  float e = __expf(2.f * x);
  return 1.f - 2.f * __builtin_amdgcn_rcpf(e + 1.f);
}
__device__ inline float sigmoid_fast(float x){
  return __builtin_amdgcn_rcpf(1.f + __expf(-x));
}

// ---------------------------------------------------------------------------
__global__ void conv_k(const float* __restrict__ s, unsigned short* __restrict__ d, int n){
  int i = (blockIdx.x * 256 + threadIdx.x) * 4;
  if (i >= n) return;
  float4 v = *(const float4*)(s + i);
  *(uint2*)(d + i) = make_uint2(pack2(v.x, v.y), pack2(v.z, v.w));
}

__global__ void embed_k(const int* __restrict__ tgt, const float* __restrict__ emb,
                        unsigned short* __restrict__ out, int n){
  int idx = blockIdx.x * 256 + threadIdx.x;
  if (idx >= n) return;
  int d = idx & 511, m = idx >> 9, t = m >> 6, b = m & 63;
  int tok = tgt[b * 32 + t];
  float v = (tok == 2) ? 0.f : emb[(long)tok * 512 + d];
  out[idx] = f2b(v);
}

// pack [W_ih[:,512:1024] rows 0..1535 ; W_hh rows 0..1535] -> (3072,512) bf16
__global__ void repack_wg(const float* __restrict__ Wih, const float* __restrict__ Whh,
                          unsigned short* __restrict__ out){
  int idx = (blockIdx.x * 256 + threadIdx.x) * 4;
  if (idx >= 3072 * 512) return;
  int j = idx >> 9, k = idx & 511;
  const float* src = (j < 1536) ? (Wih + (long)j * 1024 + 512 + k)
                                : (Whh + (long)(j - 1536) * 512 + k);
  float4 v = *(const float4*)src;
  *(uint2*)(out + idx) = make_uint2(pack2(v.x, v.y), pack2(v.z, v.w));
}

// pack W_ih[:, :512] -> (1536,512) bf16
__global__ void repack_wih0(const float* __restrict__ Wih, unsigned short* __restrict__ out){
  int idx = (blockIdx.x * 256 + threadIdx.x) * 4;
  if (idx >= 1536 * 512) return;
  int j = idx >> 9, k = idx & 511;
  float4 v = *(const float4*)(Wih + (long)j * 1024 + k);
  *(uint2*)(out + idx) = make_uint2(pack2(v.x, v.y), pack2(v.z, v.w));
}

// ---------------------------------------------------------------------------
// small GEMM: C[m][n] = A[m][k]*B[n][k] + bias[n]. BM=64, BN=256, 256 thr.
#define EPI_PLAIN 0
#define EPI_TANH  1
#define EPI_B16   3

template<int EPI, bool AF32>
__global__ __launch_bounds__(256)
void gemm_bt(const void* __restrict__ Av, int lda,
             const unsigned short* __restrict__ Bp, int ldb,
             const float* __restrict__ bias,
             float* __restrict__ Cf, unsigned short* __restrict__ Cb, int ldc,
             int K)
{
  __shared__ __align__(16) unsigned short As[64][40];
  __shared__ __align__(16) unsigned short Bs[256][40];
  int m0 = blockIdx.x * 64, n0 = blockIdx.y * 256;
  int tid = threadIdx.x;
  int wave = tid >> 6, lane = tid & 63, quad = lane >> 4, lrow = lane & 15;

  f32x4 acc[4][4];
#pragma unroll
  for (int i = 0; i < 4; ++i)
#pragma unroll
    for (int j = 0; j < 4; ++j)
#pragma unroll
      for (int r = 0; r < 4; ++r) acc[i][j][r] = 0.f;

  int ar = tid >> 2, ac = (tid & 3) * 8;

  for (int k0 = 0; k0 < K; k0 += 32){
    if (AF32){
      const float* A32 = (const float*)Av;
      const float4* src = (const float4*)(A32 + (long)(m0 + ar) * lda + k0 + ac);
      float4 x0 = src[0], x1 = src[1];
      *(uint4*)&As[ar][ac] = make_uint4(pack2(x0.x, x0.y), pack2(x0.z, x0.w),
                                        pack2(x1.x, x1.y), pack2(x1.z, x1.w));
    } else {
      const unsigned short* A16 = (const unsigned short*)Av;
      *(uint4*)&As[ar][ac] = *(const uint4*)(A16 + (long)(m0 + ar) * lda + k0 + ac);
    }
#pragma unroll
    for (int c = 0; c < 4; ++c){
      int id = tid + c * 256; int br = id >> 2, bc = (id & 3) * 8;
      *(uint4*)&Bs[br][bc] = *(const uint4*)(Bp + (long)(n0 + br) * ldb + k0 + bc);
    }
    __syncthreads();
    bf16x8 af[4], bfr[4];
#pragma unroll
    for (int mf = 0; mf < 4; ++mf) af[mf]  = *(const bf16x8*)&As[mf * 16 + lrow][quad * 8];
#pragma unroll
    for (int nf = 0; nf < 4; ++nf) bfr[nf] = *(const bf16x8*)&Bs[wave * 64 + nf * 16 + lrow][quad * 8];
#pragma unroll
    for (int mf = 0; mf < 4; ++mf)
#pragma unroll
      for (int nf = 0; nf < 4; ++nf)
        acc[mf][nf] = __builtin_amdgcn_mfma_f32_16x16x32_bf16(af[mf], bfr[nf], acc[mf][nf], 0, 0, 0);
    __syncthreads();
  }

#pragma unroll
  for (int mf = 0; mf < 4; ++mf)
#pragma unroll
    for (int nf = 0; nf < 4; ++nf)
#pragma unroll
      for (int r = 0; r < 4; ++r){
        int m = m0 + mf * 16 + quad * 4 + r;
        int n = n0 + wave * 64 + nf * 16 + lrow;
        float v = acc[mf][nf][r] + (bias ? bias[n] : 0.f);
        if (EPI == EPI_TANH){
          v = tanhf(v);
          Cf[(long)m * ldc + n] = v;
          Cb[(long)m * ldc + n] = f2b(v);
        } else if (EPI == EPI_B16){
          Cb[(long)m * ldc + n] = f2b(v);
        } else {
          Cf[(long)m * ldc + n] = v;
        }
      }
}

// ---------------------------------------------------------------------------
// logits GEMM: BM=128, BN=256, 256 thr (4 waves, 2x2), scatter (b,t,v)
__global__ __launch_bounds__(256)
void gemm_out(const unsigned short* __restrict__ A,  // 2048 rows readable
              const unsigned short* __restrict__ B,  // (32000,512)
              const float* __restrict__ bias,
              float* __restrict__ out)
{
  __shared__ __align__(16) unsigned short As[128][40];
  __shared__ __align__(16) unsigned short Bs[256][40];
  int m0 = blockIdx.x * 128, n0 = blockIdx.y * 256;
  int tid = threadIdx.x;
  int wave = tid >> 6, lane = tid & 63, quad = lane >> 4, lrow = lane & 15;
  int wm = wave >> 1, wn = wave & 1;

  f32x4 acc[4][8];
#pragma unroll
  for (int i = 0; i < 4; ++i)
#pragma unroll
    for (int j = 0; j < 8; ++j)
#pragma unroll
      for (int r = 0; r < 4; ++r) acc[i][j][r] = 0.f;

  int ar = tid >> 1, ac = (tid & 1) * 16;

  for (int k0 = 0; k0 < 512; k0 += 32){
    const unsigned short* as = A + (long)(m0 + ar) * 512 + k0 + ac;
    *(uint4*)&As[ar][ac]     = *(const uint4*)(as);
    *(uint4*)&As[ar][ac + 8] = *(const uint4*)(as + 8);
#pragma unroll
    for (int c = 0; c < 4; ++c){
      int id = tid + c * 256; int br = id >> 2, bc = (id & 3) * 8;
      *(uint4*)&Bs[br][bc] = *(const uint4*)(B + (long)(n0 + br) * 512 + k0 + bc);
    }
    __syncthreads();
    bf16x8 af[4], bfr[8];
#pragma unroll
    for (int mf = 0; mf < 4; ++mf) af[mf]  = *(const bf16x8*)&As[wm * 64 + mf * 16 + lrow][quad * 8];
#pragma unroll
    for (int nf = 0; nf < 8; ++nf) bfr[nf] = *(const bf16x8*)&Bs[wn * 128 + nf * 16 + lrow][quad * 8];
#pragma unroll
    for (int mf = 0; mf < 4; ++mf)
#pragma unroll
      for (int nf = 0; nf < 8; ++nf)
        acc[mf][nf] = __builtin_amdgcn_mfma_f32_16x16x32_bf16(af[mf], bfr[nf], acc[mf][nf], 0, 0, 0);
    __syncthreads();
  }

#pragma unroll
  for (int mf = 0; mf < 4; ++mf)
#pragma unroll
    for (int nf = 0; nf < 8; ++nf)
#pragma unroll
      for (int r = 0; r < 4; ++r){
        int m = m0 + wm * 64 + mf * 16 + quad * 4 + r;
        if (m < 1984){
          int n = n0 + wn * 128 + nf * 16 + lrow;
          out[(long)(m & 63) * 992000 + (long)(m >> 6) * 32000 + n] = acc[mf][nf][r] + bias[n];
        }
      }
}

// ---------------------------------------------------------------------------
// Persistent per-batch recurrence: 64 blocks x 1024 threads, all 31 steps.
__global__ __launch_bounds__(1024)
void recur_k(const unsigned short* __restrict__ enc_proj16, // (B,196,256)
             const unsigned short* __restrict__ enc_out16,  // (B,196,512)
             const float* __restrict__ W_score,             // 256
             const float* __restrict__ b_dec,               // 256
             const float* __restrict__ b_hh,                // 1536
             const unsigned short* __restrict__ gi_emb16,   // (31,64,1536) incl b_ih, bf16
             const float* __restrict__ h0,                  // (64,512)
             const unsigned short* __restrict__ Wdec16,     // (256,512)
             const unsigned short* __restrict__ Wg16,       // (3072,512)
             unsigned short* __restrict__ h_b16)            // rows t*64+b
{
  int b = blockIdx.x, tid = threadIdx.x;
  __shared__ __align__(16) float sh[512];
  __shared__ __align__(16) float sdp[256];
  __shared__ __align__(16) float sw[256];
  __shared__ __align__(16) float sgq[3072];
  __shared__ __align__(16) float sred[1024];
  __shared__ __align__(16) float swred[16];
  __shared__ __align__(16) float swsc[256];
  __shared__ __align__(16) unsigned int shpk[256];
  __shared__ __align__(16) unsigned int scpk[256];

  if (tid < 512) sh[tid] = h0[b * 512 + tid];
  if (tid < 256) swsc[tid] = W_score[tid];
  __syncthreads();
  if (tid < 256) shpk[tid] = pack2(sh[2 * tid], sh[2 * tid + 1]);
  __syncthreads();

  for (int t = 0; t < 31; ++t){
    // ---- A: dec_proj[a] = h . Wdec[a] + b_dec[a]
    {
      int a = tid >> 2, q = tid & 3;
      const unsigned short* wd = Wdec16 + a * 512 + q * 128;
      float acc = 0.f;
#pragma unroll 8
      for (int i = 0; i < 16; ++i){
        uint4 wv = *(const uint4*)(wd + i * 8);
        uint4 hv = *(const uint4*)&shpk[q * 64 + i * 4];
        acc = dot2p(wv.x, hv.x, acc);
        acc = dot2p(wv.y, hv.y, acc);
        acc = dot2p(wv.z, hv.z, acc);
        acc = dot2p(wv.w, hv.w, acc);
      }
      acc += __shfl_xor(acc, 1);
      acc += __shfl_xor(acc, 2);
      if (q == 0) sdp[a] = acc + b_dec[a];
    }
    __syncthreads();

    // ---- B: scores + softmax
    {
      int s = tid & 255, q = tid >> 8;
      float acc = 0.f;
      if (s < 196){
        const uint4* ep = (const uint4*)(enc_proj16 + ((b * 196 + s) << 8) + (q << 6));
#pragma unroll
        for (int i = 0; i < 8; ++i){
          uint4 wv = ep[i];
          int o = q * 64 + i * 8;
          float4 d0 = *(const float4*)&sdp[o];
          float4 d1 = *(const float4*)&sdp[o + 4];
          float4 w0 = *(const float4*)&swsc[o];
          float4 w1 = *(const float4*)&swsc[o + 4];
          acc = fmaf(w0.x, tanh_fast(bflo(wv.x) + d0.x), acc);
          acc = fmaf(w0.y, tanh_fast(bfhi(wv.x) + d0.y), acc);
          acc = fmaf(w0.z, tanh_fast(bflo(wv.y) + d0.z), acc);
          acc = fmaf(w0.w, tanh_fast(bfhi(wv.y) + d0.w), acc);
          acc = fmaf(w1.x, tanh_fast(bflo(wv.z) + d1.x), acc);
          acc = fmaf(w1.y, tanh_fast(bfhi(wv.z) + d1.y), acc);
          acc = fmaf(w1.z, tanh_fast(bflo(wv.w) + d1.z), acc);
          acc = fmaf(w1.w, tanh_fast(bfhi(wv.w) + d1.w), acc);
        }
      }
      sred[tid] = acc;
      __syncthreads();
      float sc = -1e30f;
      if (tid < 196) sc = sred[tid] + sred[tid + 256] + sred[tid + 512] + sred[tid + 768];
      float mx = sc;
#pragma unroll
      for (int o = 32; o >= 1; o >>= 1) mx = fmaxf(mx, __shfl_xor(mx, o));
      if (tid < 256 && (tid & 63) == 0) swred[tid >> 6] = mx;
      __syncthreads();
      mx = fmaxf(fmaxf(swred[0], swred[1]), fmaxf(swred[2], swred[3]));
      float ev = (tid < 196) ? __expf(sc - mx) : 0.f;
      float sm = ev;
#pragma unroll
      for (int o = 32; o >= 1; o >>= 1) sm += __shfl_xor(sm, o);
      if (tid < 256 && (tid & 63) == 0) swred[8 + (tid >> 6)] = sm;
      __syncthreads();
      float inv = __builtin_amdgcn_rcpf(swred[8] + swred[9] + swred[10] + swred[11]);
      if (tid < 196) sw[tid] = ev * inv;
    }
    __syncthreads();

    // ---- C: ctx[e] = sum_s w[s] * enc_out[b,s,e]
    {
      int e = tid & 511, q = tid >> 9;
      const unsigned short* ebase = enc_out16 + ((b * 196 + q * 98) << 9) + e;
      float acc = 0.f;
#pragma unroll 7
      for (int i = 0; i < 98; ++i)
        acc = fmaf(sw[q * 98 + i], bf2f(ebase[i * 512]), acc);
      sred[tid] = acc;
      __syncthreads();
      if (tid < 512) sred[tid] = sred[tid] + sred[tid + 512];
      __syncthreads();
      if (tid < 256) scpk[tid] = pack2(sred[2 * tid], sred[2 * tid + 1]);
    }
    __syncthreads();

    // ---- D: giq = [Wihc.ctx (1536) ; Whh.h (1536)], 3 rows/thread
    {
      const unsigned short* w0 = Wg16 + (long)tid * 512;
      const unsigned short* w1 = w0 + 1024 * 512;
      const unsigned short* w2 = w0 + 2048 * 512;
      bool mid_ctx = (tid < 512);
      float a0 = 0.f, a1 = 0.f, a2 = 0.f;
#pragma unroll 4
      for (int i = 0; i < 64; ++i){
        uint4 x0 = *(const uint4*)(w0 + i * 8);
        uint4 x1 = *(const uint4*)(w1 + i * 8);
        uint4 x2 = *(const uint4*)(w2 + i * 8);
        uint4 oc = *(const uint4*)&scpk[i * 4];
        uint4 oh = *(const uint4*)&shpk[i * 4];
        uint4 om = mid_ctx ? oc : oh;
        a0 = dot2p(x0.x, oc.x, a0); a0 = dot2p(x0.y, oc.y, a0);
        a0 = dot2p(x0.z, oc.z, a0); a0 = dot2p(x0.w, oc.w, a0);
        a1 = dot2p(x1.x, om.x, a1); a1 = dot2p(x1.y, om.y, a1);
        a1 = dot2p(x1.z, om.z, a1); a1 = dot2p(x1.w, om.w, a1);
        a2 = dot2p(x2.x, oh.x, a2); a2 = dot2p(x2.y, oh.y, a2);
        a2 = dot2p(x2.z, oh.z, a2); a2 = dot2p(x2.w, oh.w, a2);
      }
      sgq[tid] = a0; sgq[tid + 1024] = a1; sgq[tid + 2048] = a2;
    }
    __syncthreads();

    // ---- E: gates -> h_{t+1}
    if (tid < 512){
      int j = tid;
      const unsigned short* ge = gi_emb16 + (long)(t * 64 + b) * 1536;
      float gir = bf2f(ge[j])        + sgq[j];
      float giz = bf2f(ge[j + 512])  + sgq[j + 512];
      float gin = bf2f(ge[j + 1024]) + sgq[j + 1024];
      float ghr = sgq[1536 + j] + b_hh[j];
      float ghz = sgq[2048 + j] + b_hh[512 + j];
      float ghn = sgq[2560 + j] + b_hh[1024 + j];
      float r = sigmoid_fast(gir + ghr);
      float z = sigmoid_fast(giz + ghz);
      float n = tanh_fast(gin + r * ghn);
      float hn = (1.f - z) * n + z * sh[j];
      sh[j] = hn;
      h_b16[(long)((t + 1) * 64 + b) * 512 + j] = f2b(hn);
    }
    __syncthreads();
    if (tid < 256) shpk[tid] = pack2(sh[2 * tid], sh[2 * tid + 1]);
    __syncthreads();
  }
}

// ---------------------------------------------------------------------------
extern "C" void kernel_launch(void* const* d_in, const int* in_sizes, int n_in,
                              void* d_out, int out_size, void* d_ws, size_t ws_size,
                              hipStream_t stream)
{
  (void)in_sizes; (void)n_in; (void)out_size; (void)ws_size;
  const float* encoder_out = (const float*)d_in[0];
  const float* pooled      = (const float*)d_in[1];
  const int*   targets     = (const int*)d_in[2];
  const float* embedding   = (const float*)d_in[3];
  const float* W_enc  = (const float*)d_in[4];
  const float* b_enc  = (const float*)d_in[5];
  const float* W_dec  = (const float*)d_in[6];
  const float* b_dec  = (const float*)d_in[7];
  const float* W_score= (const float*)d_in[8];
  const float* W_ih   = (const float*)d_in[10];
  const float* W_hh   = (const float*)d_in[11];
  const float* b_ih   = (const float*)d_in[12];
  const float* b_hh   = (const float*)d_in[13];
  const float* W_out  = (const float*)d_in[14];
  const float* b_out  = (const float*)d_in[15];
  const float* W_init = (const float*)d_in[16];
  const float* b_init = (const float*)d_in[17];
  float* out = (float*)d_out;

  // all sizes in BYTES (R2 bug: enc_out16 was reserved in elements)
  char* w = (char*)d_ws;
  unsigned short* enc_proj16 = (unsigned short*)w; w += 6422528;   // (12544,256) bf16
  unsigned short* gi_emb16   = (unsigned short*)w; w += 6094848;   // (31,64,1536) bf16
  float* h0f                 = (float*)w;          w += 131072;    // (64,512) f32
  unsigned short* h_b16      = (unsigned short*)w; w += 2162688;   // 2112 rows x 512 bf16
  unsigned short* emb_b16    = (unsigned short*)w; w += 2031616;   // (1984,512) bf16
  unsigned short* enc_out16  = (unsigned short*)w; w += 12845056;  // (64,196,512) bf16
  unsigned short* Wout_b     = (unsigned short*)w; w += 32768000;  // (32000,512) bf16
  unsigned short* Wihe_b     = (unsigned short*)w; w += 1572864;   // (1536,512)  bf16
  unsigned short* Wdec_b     = (unsigned short*)w; w += 262144;    // (256,512)
  unsigned short* Winit_b    = (unsigned short*)w; w += 524288;    // (512,512)
  unsigned short* Wenc_b     = (unsigned short*)w; w += 262144;    // (256,512)
  unsigned short* Wg_b       = (unsigned short*)w; w += 3145728;   // (3072,512)

  auto conv = [&](const float* s, unsigned short* d, int n){
    conv_k<<<dim3((n / 4 + 255) / 256), dim3(256), 0, stream>>>(s, d, n);
  };
  conv(W_out,  Wout_b,  32000 * 512);
  conv(W_dec,  Wdec_b,  256 * 512);
  conv(W_init, Winit_b, 512 * 512);
  conv(W_enc,  Wenc_b,  256 * 512);
  conv(encoder_out, enc_out16, 64 * 196 * 512);
  embed_k<<<dim3((1984 * 512) / 256), dim3(256), 0, stream>>>(targets, embedding, emb_b16, 1984 * 512);
  repack_wg<<<dim3(3072 * 512 / 4 / 256), dim3(256), 0, stream>>>(W_ih, W_hh, Wg_b);
  repack_wih0<<<dim3(1536 * 512 / 4 / 256), dim3(256), 0, stream>>>(W_ih, Wihe_b);

  // h0 = tanh(pooled @ W_init^T + b_init) -> f32 + bf16 (rows 0..63 of h_b16)
  gemm_bt<EPI_TANH, true><<<dim3(1, 2), 256, 0, stream>>>(
      pooled, 512, Winit_b, 512, b_init, h0f, h_b16, 512, 512);
  // enc_proj16 = bf16(encoder_out @ W_enc^T + b_enc)
  gemm_bt<EPI_B16, true><<<dim3(196, 1), 256, 0, stream>>>(
      encoder_out, 512, Wenc_b, 512, b_enc, nullptr, enc_proj16, 256, 512);
  // gi_emb16 = bf16(embedded @ W_ih[:,:512]^T + b_ih)
  gemm_bt<EPI_B16, false><<<dim3(31, 6), 256, 0, stream>>>(
      emb_b16, 512, Wihe_b, 512, b_ih, nullptr, gi_emb16, 1536, 512);

  // the whole 31-step recurrence, one launch
  recur_k<<<dim3(64), dim3(1024), 0, stream>>>(
      enc_proj16, enc_out16, W_score, b_dec, b_hh, gi_emb16, h0f,
      Wdec_b, Wg_b, h_b16);

  // logits: (1984 x 32000 x 512), A = h_1..h_31 (rows 64.., padded to 2048)
  gemm_out<<<dim3(16, 125), 256, 0, stream>>>(
      h_b16 + 64 * 512, Wout_b, b_out, out);
}